// Round 13
// baseline (792.666 us; speedup 1.0000x reference)
//
#include <hip/hip_runtime.h>
#include <hip/hip_bf16.h>

#define S_DIM 1024
#define R_DIM 512
#define C_DIM 256
#define BS 64
#define SB (S_DIM / BS)   // 16

#define XN_OFF (16u << 20)                       // xn cache at ws+16MB
#define XN_BYTES (512ull * 1024ull * 256ull * 2ull)  // 268435456

typedef __attribute__((ext_vector_type(8))) short short8;
typedef __attribute__((ext_vector_type(8))) unsigned short ushort8v;
typedef __attribute__((ext_vector_type(4))) unsigned short ushort4v;
typedef __attribute__((ext_vector_type(4))) float floatx4;

__device__ inline float bf2f(unsigned short u) {
    return __uint_as_float(((unsigned int)u) << 16);
}
__device__ inline unsigned short f2bf(float f) {
    unsigned int x = __float_as_uint(f);
    unsigned int r = ((x >> 16) & 1u) + 0x7fffu;
    return (unsigned short)((x + r) >> 16);
}

// v_rcp_f32: ~1ulp approx reciprocal; avoids the IEEE divide sequence.
__device__ inline float fast_rcp(float x) {
    float r;
    asm volatile("v_rcp_f32 %0, %1" : "=v"(r) : "v"(x));
    return r;
}

__device__ inline void async16nt(unsigned short* lds, const unsigned short* g) {
    // aux=2 -> NT cache policy; safe: every 16-lane group covers full lines.
    __builtin_amdgcn_global_load_lds(
        (const __attribute__((address_space(1))) void*)g,
        (__attribute__((address_space(3))) void*)lds, 16, 0, 2);
}

// ---------------- prep: build transposed bf16 weight copies ----------------
__global__ __launch_bounds__(256) void prep_kernel(
        const float* __restrict__ Wk, const float* __restrict__ Wv,
        const float* __restrict__ Wg, const float* __restrict__ Wf,
        unsigned short* __restrict__ wgT, unsigned short* __restrict__ wfhi,
        unsigned short* __restrict__ wflo, unsigned short* __restrict__ wkvT) {
    int b = blockIdx.x;    // output column index (0..255)
    int k = threadIdx.x;   // k index (0..255)
    wgT[b * 256 + k] = f2bf(Wg[k * 256 + b]);
    float w = Wf[k * 256 + b];
    unsigned short hi = f2bf(w);
    wfhi[b * 256 + k] = hi;
    wflo[b * 256 + k] = f2bf(w - bf2f(hi));
    if (b < 64) {
        float t = (b < 32) ? Wk[k * 32 + b] : Wv[k * 32 + (b - 32)];
        wkvT[b * 256 + k] = f2bf(t);
    }
}

// ---------------- K1a: pure-streaming LayerNorm x -> xnws (bf16) -----------
__global__ __launch_bounds__(256, 4) void k1a_kernel(
        const float* __restrict__ x, const float* __restrict__ lns,
        const float* __restrict__ lnb, unsigned short* __restrict__ xnws) {
    const int t = threadIdx.x;
    const int row = t >> 3;           // 0..31 within block
    const int q = t & 7;              // 32-float chunk within the 256-row
    const size_t base = ((size_t)blockIdx.x * 32 + row) * 256 + q * 32;
    const floatx4* gp = reinterpret_cast<const floatx4*>(x + base);
    floatx4 v[8];
    float sum = 0.f, sq = 0.f;
#pragma unroll
    for (int i = 0; i < 8; i++) {
        v[i] = gp[i];
        sum += v[i][0] + v[i][1] + v[i][2] + v[i][3];
        sq  += v[i][0] * v[i][0] + v[i][1] * v[i][1]
             + v[i][2] * v[i][2] + v[i][3] * v[i][3];
    }
    sum += __shfl_xor(sum, 1); sq += __shfl_xor(sq, 1);
    sum += __shfl_xor(sum, 2); sq += __shfl_xor(sq, 2);
    sum += __shfl_xor(sum, 4); sq += __shfl_xor(sq, 4);
    float mu = sum * (1.f / 256.f);
    float var = sq * (1.f / 256.f) - mu * mu;
    float rs = rsqrtf(var + 1e-5f);
    const floatx4* sp = reinterpret_cast<const floatx4*>(lns + q * 32);
    const floatx4* bp = reinterpret_cast<const floatx4*>(lnb + q * 32);
    unsigned short* gw = xnws + base;
#pragma unroll
    for (int i = 0; i < 8; i += 2) {
        floatx4 g0 = sp[i],     b0 = bp[i];
        floatx4 g1 = sp[i + 1], b1 = bp[i + 1];
        ushort8v u;
        u[0] = f2bf((v[i][0]     - mu) * rs * g0[0] + b0[0]);
        u[1] = f2bf((v[i][1]     - mu) * rs * g0[1] + b0[1]);
        u[2] = f2bf((v[i][2]     - mu) * rs * g0[2] + b0[2]);
        u[3] = f2bf((v[i][3]     - mu) * rs * g0[3] + b0[3]);
        u[4] = f2bf((v[i + 1][0] - mu) * rs * g1[0] + b1[0]);
        u[5] = f2bf((v[i + 1][1] - mu) * rs * g1[1] + b1[1]);
        u[6] = f2bf((v[i + 1][2] - mu) * rs * g1[2] + b1[2]);
        u[7] = f2bf((v[i + 1][3] - mu) * rs * g1[3] + b1[3]);
        *reinterpret_cast<ushort8v*>(gw + i * 4) = u;   // cached: L2 merges
    }
}

// ---------------- K1b: kv + masked column sums from xnws -------------------
__global__ __launch_bounds__(256, 4) void k1b_kernel(
        const unsigned short* __restrict__ xnws, const float* __restrict__ mask,
        const unsigned short* __restrict__ wkvT, unsigned short* __restrict__ kv,
        float* __restrict__ qsum, float* __restrict__ msum) {
    __shared__ unsigned short xn[64 * 256];   // chunk' = chunk ^ (row&7)
    __shared__ float mk[64];
    const int sblk = blockIdx.x, r = blockIdx.y;
    const int s0 = sblk * BS;
    const int t = threadIdx.x;
    const int w = t >> 6, l = t & 63;

    {   // async stage: wave w rows 16w..16w+15; LDS linear, source pre-swizzled
        const int c1 = l & 31;
        const int rh = l >> 5;
#pragma unroll
        for (int j = 0; j < 8; j++) {
            int row = w * 16 + 2 * j + rh;
            size_t src = ((size_t)(s0 + row) * R_DIM + r) * C_DIM
                         + (size_t)((c1 ^ (row & 7)) * 8);
            async16nt(xn + (w * 16 + 2 * j) * 256, xnws + src);
        }
    }
    if (t < 64) mk[t] = mask[(size_t)(s0 + t) * R_DIM + r];
    __syncthreads();

    // MFMA: wave w -> rows 16w..16w+15, cols 0..63 (= [k | v])
    const int lr = l & 15, lk4 = l >> 4;
    const int sw = lr & 7;   // row&7 for row = w*16+lr
    floatx4 acc[4] = {};
#pragma unroll
    for (int kk = 0; kk < 256; kk += 32) {
        const int ch = (((kk >> 3) + lk4) ^ sw) * 8;
        short8 a = *reinterpret_cast<const short8*>(xn + (w * 16 + lr) * 256 + ch);
#pragma unroll
        for (int n = 0; n < 4; n++) {
            short8 b = *reinterpret_cast<const short8*>(wkvT + (n * 16 + lr) * 256 + kk + lk4 * 8);
            acc[n] = __builtin_amdgcn_mfma_f32_16x16x32_bf16(a, b, acc[n], 0, 0, 0);
        }
    }
    unsigned short* kvp = kv + ((size_t)r * S_DIM + s0) * 64;
#pragma unroll
    for (int n = 0; n < 4; n++) {
        int col = n * 16 + lr;
#pragma unroll
        for (int i = 0; i < 4; i++) {
            int row = w * 16 + lk4 * 4 + i;
            kvp[(size_t)row * 64 + col] = f2bf(acc[n][i]);
        }
    }
    // masked column sums over the 64 rows (swizzled column read)
    {
        const int c = t;
        const int chi = c >> 3, clo = c & 7;
        float cs = 0.f;
#pragma unroll 8
        for (int row = 0; row < 64; row++)
            cs += bf2f(xn[row * 256 + ((chi ^ (row & 7)) * 8 + clo)]) * mk[row];
        qsum[((size_t)r * SB + sblk) * 256 + c] = cs;
    }
    if (t < 64) {
        float m = mk[t];
#pragma unroll
        for (int off = 32; off; off >>= 1) m += __shfl_xor(m, off);
        if (t == 0) msum[r * SB + sblk] = m;
    }
}

// ---------------- K1 (fallback, fused, small-ws path) ----------------------
__global__ __launch_bounds__(256, 4) void k1_old_kernel(
        const float* __restrict__ x, const float* __restrict__ mask,
        const float* __restrict__ lns, const float* __restrict__ lnb,
        const unsigned short* __restrict__ wkvT, unsigned short* __restrict__ kv,
        float* __restrict__ qsum, float* __restrict__ msum) {
    __shared__ unsigned short xn[64 * 264];
    __shared__ float mk[64];
    const int sblk = blockIdx.x, r = blockIdx.y;
    const int s0 = sblk * BS;
    const int t = threadIdx.x;
    {
        const int row = t >> 2;
        const int q = t & 3;
        const size_t base = ((size_t)(s0 + row) * R_DIM + r) * C_DIM + q * 64;
        const floatx4* gp = reinterpret_cast<const floatx4*>(x + base);
        floatx4 v[16];
        float sum = 0.f, sq = 0.f;
#pragma unroll
        for (int i = 0; i < 16; i++) {
            v[i] = gp[i];
            sum += v[i][0] + v[i][1] + v[i][2] + v[i][3];
            sq  += v[i][0] * v[i][0] + v[i][1] * v[i][1] + v[i][2] * v[i][2] + v[i][3] * v[i][3];
        }
        sum += __shfl_xor(sum, 1); sq += __shfl_xor(sq, 1);
        sum += __shfl_xor(sum, 2); sq += __shfl_xor(sq, 2);
        float mu = sum * (1.f / 256.f);
        float var = sq * (1.f / 256.f) - mu * mu;
        float rs = rsqrtf(var + 1e-5f);
        const floatx4* sp = reinterpret_cast<const floatx4*>(lns + q * 64);
        const floatx4* bp = reinterpret_cast<const floatx4*>(lnb + q * 64);
        unsigned short* wp = xn + row * 264 + q * 64;
#pragma unroll
        for (int i = 0; i < 16; i += 2) {
            floatx4 g0 = sp[i],     b0 = bp[i];
            floatx4 g1 = sp[i + 1], b1 = bp[i + 1];
            ushort8v u;
            u[0] = f2bf((v[i][0]     - mu) * rs * g0[0] + b0[0]);
            u[1] = f2bf((v[i][1]     - mu) * rs * g0[1] + b0[1]);
            u[2] = f2bf((v[i][2]     - mu) * rs * g0[2] + b0[2]);
            u[3] = f2bf((v[i][3]     - mu) * rs * g0[3] + b0[3]);
            u[4] = f2bf((v[i + 1][0] - mu) * rs * g1[0] + b1[0]);
            u[5] = f2bf((v[i + 1][1] - mu) * rs * g1[1] + b1[1]);
            u[6] = f2bf((v[i + 1][2] - mu) * rs * g1[2] + b1[2]);
            u[7] = f2bf((v[i + 1][3] - mu) * rs * g1[3] + b1[3]);
            *reinterpret_cast<ushort8v*>(wp + i * 4) = u;
        }
    }
    if (t < 64) mk[t] = mask[(size_t)(s0 + t) * R_DIM + r];
    __syncthreads();

    const int w = t >> 6, l = t & 63;
    const int lr = l & 15, lk = (l >> 4) * 8;
    floatx4 acc[4] = {};
    const unsigned short* arow = xn + (w * 16 + lr) * 264;
#pragma unroll
    for (int kk = 0; kk < 256; kk += 32) {
        short8 a = *reinterpret_cast<const short8*>(arow + kk + lk);
#pragma unroll
        for (int n = 0; n < 4; n++) {
            short8 b = *reinterpret_cast<const short8*>(wkvT + (n * 16 + lr) * 256 + kk + lk);
            acc[n] = __builtin_amdgcn_mfma_f32_16x16x32_bf16(a, b, acc[n], 0, 0, 0);
        }
    }
    unsigned short* kvp = kv + ((size_t)r * S_DIM + s0) * 64;
#pragma unroll
    for (int n = 0; n < 4; n++) {
        int col = n * 16 + lr;
#pragma unroll
        for (int i = 0; i < 4; i++) {
            int row = w * 16 + (l >> 4) * 4 + i;
            kvp[(size_t)row * 64 + col] = f2bf(acc[n][i]);
        }
    }
    float cs = 0.f;
    const int c = t;
#pragma unroll 8
    for (int row = 0; row < 64; row++) cs += bf2f(xn[row * 264 + c]) * mk[row];
    qsum[((size_t)r * SB + sblk) * 256 + c] = cs;
    if (t < 64) {
        float m = mk[t];
#pragma unroll
        for (int off = 32; off; off >>= 1) m += __shfl_xor(m, off);
        if (t == 0) msum[r * SB + sblk] = m;
    }
}

// ---------------- K2: q_avg, q, softmax (barrier-free), o ------------------
__global__ __launch_bounds__(256) void k2_kernel(
        const float* __restrict__ mask, const float* __restrict__ Wq,
        const float* __restrict__ qsum, const float* __restrict__ msum,
        const unsigned short* __restrict__ kv, float* __restrict__ oout) {
    __shared__ float qavg[256];
    __shared__ float qh[256];
    __shared__ float lg[8][1024];
    __shared__ unsigned short vt[256 * 36];   // v tile, padded rows (72 B)
    const int r = blockIdx.x;
    const int t = threadIdx.x;

    float ms = 0.f;
#pragma unroll
    for (int i = 0; i < SB; i++) ms += msum[r * SB + i];
    float inv = 1.f / (ms + 1e-10f);
    float qs = 0.f;
#pragma unroll
    for (int i = 0; i < SB; i++) qs += qsum[((size_t)r * SB + i) * 256 + t];
    qavg[t] = qs * inv;
    __syncthreads();

    float accq = 0.f;
#pragma unroll 8
    for (int c = 0; c < 256; c++) accq += qavg[c] * Wq[c * 256 + t];
    qh[t] = accq * 0.17677669529663687f;   // CH^-0.5
    __syncthreads();

    const unsigned short* kvr = kv + (size_t)r * S_DIM * 64;
#pragma unroll
    for (int i = 0; i < 4; i++) {
        int s = i * 256 + t;
        float bias = 1e9f * (mask[(size_t)s * R_DIM + r] - 1.f);
        const unsigned int* kp = reinterpret_cast<const unsigned int*>(kvr + (size_t)s * 64);
        float kvals[32];
#pragma unroll
        for (int j = 0; j < 16; j++) {
            unsigned int u = kp[j];
            kvals[2 * j]     = __uint_as_float(u << 16);
            kvals[2 * j + 1] = __uint_as_float(u & 0xffff0000u);
        }
#pragma unroll
        for (int h = 0; h < 8; h++) {
            float d = 0.f;
#pragma unroll
            for (int ch = 0; ch < 32; ch++) d += qh[h * 32 + ch] * kvals[ch];
            lg[h][s] = d + bias;
        }
    }
    __syncthreads();

    // barrier-free softmax: head = t>>5 (half-wave group), rotated bank access
    {
        const int h = t >> 5;
        const int g = t & 31;
        float* lrow = &lg[h][0];
        float mx = -1e30f;
#pragma unroll
        for (int j = 0; j < 32; j++)
            mx = fmaxf(mx, lrow[g * 32 + ((j + g) & 31)]);
#pragma unroll
        for (int off = 16; off; off >>= 1) mx = fmaxf(mx, __shfl_xor(mx, off));
        float vals[32];
        float sm = 0.f;
#pragma unroll
        for (int j = 0; j < 32; j++) {
            float e = __expf(lrow[g * 32 + ((j + g) & 31)] - mx);
            vals[j] = e;
            sm += e;
        }
#pragma unroll
        for (int off = 16; off; off >>= 1) sm += __shfl_xor(sm, off);
        float isv = 1.f / sm;
#pragma unroll
        for (int j = 0; j < 32; j++)
            lrow[g * 32 + ((j + g) & 31)] = vals[j] * isv;
    }
    __syncthreads();

    // o = w @ v via LDS-staged v tiles (broadcast reads)
    const int h = t >> 5, ch = t & 31;
    float o = 0.f;
    for (int st = 0; st < 4; st++) {
        __syncthreads();
        {
            const unsigned short* src = kvr + ((size_t)(st * 256 + t)) * 64 + 32;
            ushort4v* dst = reinterpret_cast<ushort4v*>(vt + t * 36);
#pragma unroll
            for (int j = 0; j < 8; j++)
                dst[j] = *reinterpret_cast<const ushort4v*>(src + 4 * j);
        }
        __syncthreads();
#pragma unroll 8
        for (int sl = 0; sl < 256; sl++)
            o += lg[h][sl + st * 256] * bf2f(vt[sl * 36 + ch]);
    }
    oout[r * 256 + t] = o;
}

// ---------------- K3 (recompute path, fallback) ----------------------------
__global__ __launch_bounds__(256, 4) void k3r_kernel(
        const float* __restrict__ x, const float* __restrict__ lns,
        const float* __restrict__ lnb, const unsigned short* __restrict__ wgT,
        const unsigned short* __restrict__ wfhi, const unsigned short* __restrict__ wflo,
        const float* __restrict__ oin, const float* __restrict__ bg,
        const float* __restrict__ bfv, float* __restrict__ out) {
    __shared__ unsigned short xa[64 * 264];
    const int sblk = blockIdx.x, r = blockIdx.y;
    const int s0 = sblk * BS;
    const int t = threadIdx.x;
    {
        const int row = t >> 2;
        const int q = t & 3;
        const size_t base = ((size_t)(s0 + row) * R_DIM + r) * C_DIM + q * 64;
        const floatx4* gp = reinterpret_cast<const floatx4*>(x + base);
        floatx4 v[16];
        float sum = 0.f, sq = 0.f;
#pragma unroll
        for (int i = 0; i < 16; i++) {
            v[i] = gp[i];
            sum += v[i][0] + v[i][1] + v[i][2] + v[i][3];
            sq  += v[i][0] * v[i][0] + v[i][1] * v[i][1] + v[i][2] * v[i][2] + v[i][3] * v[i][3];
        }
        sum += __shfl_xor(sum, 1); sq += __shfl_xor(sq, 1);
        sum += __shfl_xor(sum, 2); sq += __shfl_xor(sq, 2);
        float mu = sum * (1.f / 256.f);
        float var = sq * (1.f / 256.f) - mu * mu;
        float rs = rsqrtf(var + 1e-5f);
        const floatx4* sp = reinterpret_cast<const floatx4*>(lns + q * 64);
        const floatx4* bp = reinterpret_cast<const floatx4*>(lnb + q * 64);
        unsigned short* wp = xa + row * 264 + q * 64;
#pragma unroll
        for (int i = 0; i < 16; i += 2) {
            floatx4 g0 = sp[i],     b0 = bp[i];
            floatx4 g1 = sp[i + 1], b1 = bp[i + 1];
            ushort8v u;
            u[0] = f2bf((v[i][0]     - mu) * rs * g0[0] + b0[0]);
            u[1] = f2bf((v[i][1]     - mu) * rs * g0[1] + b0[1]);
            u[2] = f2bf((v[i][2]     - mu) * rs * g0[2] + b0[2]);
            u[3] = f2bf((v[i][3]     - mu) * rs * g0[3] + b0[3]);
            u[4] = f2bf((v[i + 1][0] - mu) * rs * g1[0] + b1[0]);
            u[5] = f2bf((v[i + 1][1] - mu) * rs * g1[1] + b1[1]);
            u[6] = f2bf((v[i + 1][2] - mu) * rs * g1[2] + b1[2]);
            u[7] = f2bf((v[i + 1][3] - mu) * rs * g1[3] + b1[3]);
            *reinterpret_cast<ushort8v*>(wp + i * 4) = u;
        }
    }
    __syncthreads();

    const int w = t >> 6, l = t & 63;
    const int lr = l & 15, lk4 = (l >> 4);
    const int colbase = w * 64;

    float bgv[4], ov[4];
#pragma unroll
    for (int n = 0; n < 4; n++) {
        int col = colbase + n * 16 + lr;
        bgv[n] = bg[col];
        ov[n] = oin[r * 256 + col];
    }

    floatx4 acc[4][4] = {};
#pragma unroll
    for (int kk = 0; kk < 256; kk += 32) {
        short8 a[4];
#pragma unroll
        for (int m = 0; m < 4; m++)
            a[m] = *reinterpret_cast<const short8*>(xa + (m * 16 + lr) * 264 + kk + lk4 * 8);
#pragma unroll
        for (int n = 0; n < 4; n++) {
            short8 b = *reinterpret_cast<const short8*>(wgT + (size_t)(colbase + n * 16 + lr) * 256 + kk + lk4 * 8);
#pragma unroll
            for (int m = 0; m < 4; m++)
                acc[m][n] = __builtin_amdgcn_mfma_f32_16x16x32_bf16(a[m], b, acc[m][n], 0, 0, 0);
        }
    }
    __syncthreads();

#pragma unroll
    for (int m = 0; m < 4; m++) {
#pragma unroll
        for (int n = 0; n < 4; n++) {
            int col = colbase + n * 16 + lr;
#pragma unroll
            for (int i = 0; i < 4; i++) {
                int row = m * 16 + lk4 * 4 + i;
                float e = __expf(-(acc[m][n][i] + bgv[n]));
                float g = fast_rcp(1.f + e);
                xa[row * 264 + col] = f2bf(g * ov[n]);
            }
        }
    }
    __syncthreads();

    floatx4 acc2[4][4] = {};
#pragma unroll
    for (int kk = 0; kk < 256; kk += 32) {
        short8 ah[4];
#pragma unroll
        for (int m = 0; m < 4; m++)
            ah[m] = *reinterpret_cast<const short8*>(xa + (m * 16 + lr) * 264 + kk + lk4 * 8);
#pragma unroll
        for (int n = 0; n < 4; n++) {
            const size_t boff = (size_t)(colbase + n * 16 + lr) * 256 + kk + lk4 * 8;
            short8 bh = *reinterpret_cast<const short8*>(wfhi + boff);
            short8 bl = *reinterpret_cast<const short8*>(wflo + boff);
#pragma unroll
            for (int m = 0; m < 4; m++) {
                acc2[m][n] = __builtin_amdgcn_mfma_f32_16x16x32_bf16(ah[m], bh, acc2[m][n], 0, 0, 0);
                acc2[m][n] = __builtin_amdgcn_mfma_f32_16x16x32_bf16(ah[m], bl, acc2[m][n], 0, 0, 0);
            }
        }
    }

#pragma unroll
    for (int n = 0; n < 4; n++) {
        int col = colbase + n * 16 + lr;
        float bfc = bfv[col];
#pragma unroll
        for (int m = 0; m < 4; m++) {
#pragma unroll
            for (int i = 0; i < 4; i++) {
                int row = m * 16 + lk4 * 4 + i;
                out[((size_t)(s0 + row) * R_DIM + r) * C_DIM + col] = acc2[m][n][i] + bfc;
            }
        }
    }
}

// ---------------- K3 (xn-cache path): 512 thr, 8 waves, 32-col stripes -----
// Same 64KB LDS block footprint as R12 but 8 waves/block -> 16 waves/CU
// (4/SIMD), doubling latency hiding. Each wave owns a 32-col stripe (n<2).
// Pass 1 swapped (vectorized gate), pass 2 non-swapped (full-line epilogue).
// Weight dbuf dropped: TLP now covers L2 latency; keeps VGPR under the
// (512,4) cap of 128.
__global__ __launch_bounds__(512, 4) void k3c_kernel(
        const unsigned short* __restrict__ xnws, const unsigned short* __restrict__ wgT,
        const unsigned short* __restrict__ wfhi, const unsigned short* __restrict__ wflo,
        const float* __restrict__ oin, const float* __restrict__ bg,
        const float* __restrict__ bfv, float* __restrict__ out) {
    __shared__ unsigned short xa[2][64 * 256];   // 64 KB, chunk' = chunk ^ (row&7)
    const int sblk = blockIdx.x, r = blockIdx.y;
    const int s0 = sblk * 128;
    const int t = threadIdx.x;
    const int w = t >> 6, l = t & 63;   // w in 0..7

    // async stage both tiles: wave w covers rows w*8..w*8+7 per tile
    {
        const int c1 = l & 31;
        const int rh = l >> 5;
#pragma unroll
        for (int T = 0; T < 2; T++)
#pragma unroll
            for (int j = 0; j < 4; j++) {
                int row = w * 8 + 2 * j + rh;
                size_t src = ((size_t)(s0 + T * 64 + row) * R_DIM + r) * C_DIM
                             + (size_t)((c1 ^ (row & 7)) * 8);
                async16nt(&xa[T][(w * 8 + 2 * j) * 256], xnws + src);
            }
    }

    const int lr = l & 15, lk4 = (l >> 4);
    const int colbase = w * 32;
    const int sw = lr & 7;            // row&7 for rows m*16+lr
    const int c0 = colbase + lk4 * 4; // 4-contiguous-col base for pass 1 (+n*16)

    floatx4 bg4[2], ov4[2];
    float bfc[2];
#pragma unroll
    for (int n = 0; n < 2; n++) {
        bg4[n] = *reinterpret_cast<const floatx4*>(bg + c0 + n * 16);
        ov4[n] = *reinterpret_cast<const floatx4*>(oin + r * 256 + c0 + n * 16);
        bfc[n] = bfv[colbase + n * 16 + lr];
    }
    __syncthreads();

    // ---- pass 1 (swapped): acc[T][m][n][i] = Z[m*16+lr][c0 + n*16 + i] ----
    floatx4 acc[2][4][2] = {};
    {
        const unsigned short* wgb = wgT + (size_t)(colbase + lr) * 256 + lk4 * 8;
#pragma unroll
        for (int kk = 0; kk < 256; kk += 32) {
            short8 cw[2];
#pragma unroll
            for (int n = 0; n < 2; n++)
                cw[n] = *reinterpret_cast<const short8*>(wgb + n * 4096 + kk);
            const int ch = (((kk >> 3) + lk4) ^ sw) * 8;
#pragma unroll
            for (int T = 0; T < 2; T++) {
                short8 a[4];
#pragma unroll
                for (int m = 0; m < 4; m++)
                    a[m] = *reinterpret_cast<const short8*>(&xa[T][(m * 16 + lr) * 256 + ch]);
#pragma unroll
                for (int n = 0; n < 2; n++)
#pragma unroll
                    for (int m = 0; m < 4; m++)
                        acc[T][m][n] = __builtin_amdgcn_mfma_f32_16x16x32_bf16(cw[n], a[m], acc[T][m][n], 0, 0, 0);
            }
        }
    }
    __syncthreads();

    // ---- gate: fast sigmoid -> vectorized ushort4 swizzled LDS writes ----
#pragma unroll
    for (int T = 0; T < 2; T++)
#pragma unroll
    for (int m = 0; m < 4; m++) {
        const int row = m * 16 + lr;
        unsigned short* rowp = &xa[T][row * 256];
#pragma unroll
        for (int n = 0; n < 2; n++) {
            const int cb = c0 + n * 16;
            ushort4v pk;
#pragma unroll
            for (int i = 0; i < 4; i++) {
                float e = __expf(-(acc[T][m][n][i] + ((const float*)&bg4[n])[i]));
                float g = fast_rcp(1.f + e);
                pk[i] = f2bf(g * ((const float*)&ov4[n])[i]);
            }
            const int dst = (((cb >> 3) ^ sw) * 8) + (cb & 7);
            *reinterpret_cast<ushort4v*>(rowp + dst) = pk;
        }
    }
    __syncthreads();

    // ---- pass 2 (non-swapped): acc2[T][m][n] row-major 16-col stripes ----
    floatx4 acc2[2][4][2] = {};
    {
        const unsigned short* whb = wfhi + (size_t)(colbase + lr) * 256 + lk4 * 8;
        const unsigned short* wlb = wflo + (size_t)(colbase + lr) * 256 + lk4 * 8;
#pragma unroll
        for (int kk = 0; kk < 256; kk += 32) {
            short8 chw[2], clw[2];
#pragma unroll
            for (int n = 0; n < 2; n++) {
                chw[n] = *reinterpret_cast<const short8*>(whb + n * 4096 + kk);
                clw[n] = *reinterpret_cast<const short8*>(wlb + n * 4096 + kk);
            }
            const int ch = (((kk >> 3) + lk4) ^ sw) * 8;
#pragma unroll
            for (int T = 0; T < 2; T++) {
                short8 ah[4];
#pragma unroll
                for (int m = 0; m < 4; m++)
                    ah[m] = *reinterpret_cast<const short8*>(&xa[T][(m * 16 + lr) * 256 + ch]);
#pragma unroll
                for (int n = 0; n < 2; n++)
#pragma unroll
                    for (int m = 0; m < 4; m++) {
                        acc2[T][m][n] = __builtin_amdgcn_mfma_f32_16x16x32_bf16(ah[m], chw[n], acc2[T][m][n], 0, 0, 0);
                        acc2[T][m][n] = __builtin_amdgcn_mfma_f32_16x16x32_bf16(ah[m], clw[n], acc2[T][m][n], 0, 0, 0);
                    }
            }
        }
    }

    // ---- epilogue: cached stores (lanes lr=0..15 -> 64B full lines) ----
#pragma unroll
    for (int T = 0; T < 2; T++)
#pragma unroll
    for (int n = 0; n < 2; n++) {
        int col = colbase + n * 16 + lr;
#pragma unroll
        for (int m = 0; m < 4; m++) {
#pragma unroll
            for (int i = 0; i < 4; i++) {
                int row = T * 64 + m * 16 + lk4 * 4 + i;
                out[((size_t)(s0 + row) * R_DIM + r) * C_DIM + col] = acc2[T][m][n][i] + bfc[n];
            }
        }
    }
}

extern "C" void kernel_launch(void* const* d_in, const int* in_sizes, int n_in,
                              void* d_out, int out_size, void* d_ws, size_t ws_size,
                              hipStream_t stream) {
    const float* x1   = (const float*)d_in[0];
    const float* mask = (const float*)d_in[1];
    const float* lns  = (const float*)d_in[2];
    const float* lnb  = (const float*)d_in[3];
    const float* Wq   = (const float*)d_in[4];
    const float* Wk   = (const float*)d_in[5];
    const float* Wv   = (const float*)d_in[6];
    const float* Wg   = (const float*)d_in[7];
    const float* bg   = (const float*)d_in[8];
    const float* Wf   = (const float*)d_in[9];
    const float* bfv  = (const float*)d_in[10];

    char* ws = (char*)d_ws;
    unsigned short* wgT  = (unsigned short*)(ws);                 // 128 KB
    unsigned short* wfhi = (unsigned short*)(ws + 131072);        // 128 KB
    unsigned short* wflo = (unsigned short*)(ws + 262144);        // 128 KB
    unsigned short* wkvT = (unsigned short*)(ws + 393216);        // 32 KB
    float* qsum = (float*)(ws + 425984);                          // 8 MB
    float* msum = (float*)(ws + 425984 + 8388608);                // 32 KB
    float* oo   = (float*)(ws + 425984 + 8388608 + 32768);        // 512 KB
    unsigned short* xnws = (unsigned short*)(ws + XN_OFF);        // 256 MB (if present)
    // kv scratch lives in d_out; K3 overwrites d_out only after K2 consumed kv
    unsigned short* kv = (unsigned short*)d_out;
    float* out = (float*)d_out;

    const bool big_ws = ws_size >= (size_t)XN_OFF + (size_t)XN_BYTES;

    prep_kernel<<<256, 256, 0, stream>>>(Wk, Wv, Wg, Wf, wgT, wfhi, wflo, wkvT);
    if (big_ws) {
        k1a_kernel<<<(S_DIM * R_DIM) / 32, 256, 0, stream>>>(x1, lns, lnb, xnws);
        k1b_kernel<<<dim3(SB, R_DIM), 256, 0, stream>>>(xnws, mask, wkvT, kv, qsum, msum);
        k2_kernel<<<R_DIM, 256, 0, stream>>>(mask, Wq, qsum, msum, kv, oo);
        k3c_kernel<<<dim3(SB / 2, R_DIM), 512, 0, stream>>>(xnws, wgT, wfhi, wflo, oo, bg, bfv, out);
    } else {
        k1_old_kernel<<<dim3(SB, R_DIM), 256, 0, stream>>>(x1, mask, lns, lnb, wkvT, kv, qsum, msum);
        k2_kernel<<<R_DIM, 256, 0, stream>>>(mask, Wq, qsum, msum, kv, oo);
        k3r_kernel<<<dim3(SB, R_DIM), 256, 0, stream>>>(x1, lns, lnb, wgT, wfhi, wflo, oo, bg, bfv, out);
    }
}

// Round 14
// 710.226 us; speedup vs baseline: 1.1161x; 1.1161x over previous
//
#include <hip/hip_runtime.h>
#include <hip/hip_bf16.h>

#define S_DIM 1024
#define R_DIM 512
#define C_DIM 256
#define BS 64
#define SB (S_DIM / BS)   // 16

#define XN_OFF (16u << 20)                       // xn cache at ws+16MB
#define XN_BYTES (512ull * 1024ull * 256ull * 2ull)  // 268435456

typedef __attribute__((ext_vector_type(8))) short short8;
typedef __attribute__((ext_vector_type(8))) unsigned short ushort8v;
typedef __attribute__((ext_vector_type(4))) unsigned short ushort4v;
typedef __attribute__((ext_vector_type(4))) float floatx4;

__device__ inline float bf2f(unsigned short u) {
    return __uint_as_float(((unsigned int)u) << 16);
}
__device__ inline unsigned short f2bf(float f) {
    unsigned int x = __float_as_uint(f);
    unsigned int r = ((x >> 16) & 1u) + 0x7fffu;
    return (unsigned short)((x + r) >> 16);
}

// v_rcp_f32: ~1ulp approx reciprocal; avoids the IEEE divide sequence.
__device__ inline float fast_rcp(float x) {
    float r;
    asm volatile("v_rcp_f32 %0, %1" : "=v"(r) : "v"(x));
    return r;
}

__device__ inline void async16nt(unsigned short* lds, const unsigned short* g) {
    // aux=2 -> NT cache policy; safe: every 16-lane group covers full lines.
    __builtin_amdgcn_global_load_lds(
        (const __attribute__((address_space(1))) void*)g,
        (__attribute__((address_space(3))) void*)lds, 16, 0, 2);
}

// ---------------- prep: build transposed bf16 weight copies ----------------
__global__ __launch_bounds__(256) void prep_kernel(
        const float* __restrict__ Wk, const float* __restrict__ Wv,
        const float* __restrict__ Wg, const float* __restrict__ Wf,
        unsigned short* __restrict__ wgT, unsigned short* __restrict__ wfhi,
        unsigned short* __restrict__ wflo, unsigned short* __restrict__ wkvT) {
    int b = blockIdx.x;    // output column index (0..255)
    int k = threadIdx.x;   // k index (0..255)
    wgT[b * 256 + k] = f2bf(Wg[k * 256 + b]);
    float w = Wf[k * 256 + b];
    unsigned short hi = f2bf(w);
    wfhi[b * 256 + k] = hi;
    wflo[b * 256 + k] = f2bf(w - bf2f(hi));
    if (b < 64) {
        float t = (b < 32) ? Wk[k * 32 + b] : Wv[k * 32 + (b - 32)];
        wkvT[b * 256 + k] = f2bf(t);
    }
}

// ---------------- K1a: streaming LayerNorm x -> xnws, full-line pattern ----
// Lane q handles float positions (i*8+q)*4 : per load instruction, lanes
// q=0..7 cover 128 contiguous bytes of a row (full 64B lines); per store,
// 8 lanes x 8B = full 64B line. LN sums unchanged (row = 8 lanes).
__global__ __launch_bounds__(256, 4) void k1a_kernel(
        const float* __restrict__ x, const float* __restrict__ lns,
        const float* __restrict__ lnb, unsigned short* __restrict__ xnws) {
    const int t = threadIdx.x;
    const int row = t >> 3;           // 0..31 within block
    const int q = t & 7;
    const size_t rowbase = ((size_t)blockIdx.x * 32 + row) * 256;
    const floatx4* gp = reinterpret_cast<const floatx4*>(x + rowbase);
    const floatx4* sp = reinterpret_cast<const floatx4*>(lns);
    const floatx4* bp = reinterpret_cast<const floatx4*>(lnb);
    floatx4 v[8];
    float sum = 0.f, sq = 0.f;
#pragma unroll
    for (int i = 0; i < 8; i++) {
        v[i] = gp[i * 8 + q];
        sum += v[i][0] + v[i][1] + v[i][2] + v[i][3];
        sq  += v[i][0] * v[i][0] + v[i][1] * v[i][1]
             + v[i][2] * v[i][2] + v[i][3] * v[i][3];
    }
    sum += __shfl_xor(sum, 1); sq += __shfl_xor(sq, 1);
    sum += __shfl_xor(sum, 2); sq += __shfl_xor(sq, 2);
    sum += __shfl_xor(sum, 4); sq += __shfl_xor(sq, 4);
    float mu = sum * (1.f / 256.f);
    float var = sq * (1.f / 256.f) - mu * mu;
    float rs = rsqrtf(var + 1e-5f);
    unsigned short* gw = xnws + rowbase;
#pragma unroll
    for (int i = 0; i < 8; i++) {
        floatx4 g0 = sp[i * 8 + q];
        floatx4 b0 = bp[i * 8 + q];
        ushort4v u;
        u[0] = f2bf((v[i][0] - mu) * rs * g0[0] + b0[0]);
        u[1] = f2bf((v[i][1] - mu) * rs * g0[1] + b0[1]);
        u[2] = f2bf((v[i][2] - mu) * rs * g0[2] + b0[2]);
        u[3] = f2bf((v[i][3] - mu) * rs * g0[3] + b0[3]);
        *reinterpret_cast<ushort4v*>(gw + (i * 8 + q) * 4) = u;
    }
}

// ---------------- K1b: kv + masked column sums from xnws -------------------
__global__ __launch_bounds__(256, 4) void k1b_kernel(
        const unsigned short* __restrict__ xnws, const float* __restrict__ mask,
        const unsigned short* __restrict__ wkvT, unsigned short* __restrict__ kv,
        float* __restrict__ qsum, float* __restrict__ msum) {
    __shared__ unsigned short xn[64 * 256];   // chunk' = chunk ^ (row&7)
    __shared__ float mk[64];
    const int sblk = blockIdx.x, r = blockIdx.y;
    const int s0 = sblk * BS;
    const int t = threadIdx.x;
    const int w = t >> 6, l = t & 63;

    {   // async stage: wave w rows 16w..16w+15; LDS linear, source pre-swizzled
        const int c1 = l & 31;
        const int rh = l >> 5;
#pragma unroll
        for (int j = 0; j < 8; j++) {
            int row = w * 16 + 2 * j + rh;
            size_t src = ((size_t)(s0 + row) * R_DIM + r) * C_DIM
                         + (size_t)((c1 ^ (row & 7)) * 8);
            async16nt(xn + (w * 16 + 2 * j) * 256, xnws + src);
        }
    }
    if (t < 64) mk[t] = mask[(size_t)(s0 + t) * R_DIM + r];
    __syncthreads();

    // MFMA: wave w -> rows 16w..16w+15, cols 0..63 (= [k | v])
    const int lr = l & 15, lk4 = l >> 4;
    const int sw = lr & 7;   // row&7 for row = w*16+lr
    floatx4 acc[4] = {};
#pragma unroll
    for (int kk = 0; kk < 256; kk += 32) {
        const int ch = (((kk >> 3) + lk4) ^ sw) * 8;
        short8 a = *reinterpret_cast<const short8*>(xn + (w * 16 + lr) * 256 + ch);
#pragma unroll
        for (int n = 0; n < 4; n++) {
            short8 b = *reinterpret_cast<const short8*>(wkvT + (n * 16 + lr) * 256 + kk + lk4 * 8);
            acc[n] = __builtin_amdgcn_mfma_f32_16x16x32_bf16(a, b, acc[n], 0, 0, 0);
        }
    }
    unsigned short* kvp = kv + ((size_t)r * S_DIM + s0) * 64;
#pragma unroll
    for (int n = 0; n < 4; n++) {
        int col = n * 16 + lr;
#pragma unroll
        for (int i = 0; i < 4; i++) {
            int row = w * 16 + lk4 * 4 + i;
            kvp[(size_t)row * 64 + col] = f2bf(acc[n][i]);
        }
    }
    // masked column sums over the 64 rows (swizzled column read)
    {
        const int c = t;
        const int chi = c >> 3, clo = c & 7;
        float cs = 0.f;
#pragma unroll 8
        for (int row = 0; row < 64; row++)
            cs += bf2f(xn[row * 256 + ((chi ^ (row & 7)) * 8 + clo)]) * mk[row];
        qsum[((size_t)r * SB + sblk) * 256 + c] = cs;
    }
    if (t < 64) {
        float m = mk[t];
#pragma unroll
        for (int off = 32; off; off >>= 1) m += __shfl_xor(m, off);
        if (t == 0) msum[r * SB + sblk] = m;
    }
}

// ---------------- K1 (fallback, fused, small-ws path) ----------------------
__global__ __launch_bounds__(256, 4) void k1_old_kernel(
        const float* __restrict__ x, const float* __restrict__ mask,
        const float* __restrict__ lns, const float* __restrict__ lnb,
        const unsigned short* __restrict__ wkvT, unsigned short* __restrict__ kv,
        float* __restrict__ qsum, float* __restrict__ msum) {
    __shared__ unsigned short xn[64 * 264];
    __shared__ float mk[64];
    const int sblk = blockIdx.x, r = blockIdx.y;
    const int s0 = sblk * BS;
    const int t = threadIdx.x;
    {
        const int row = t >> 2;
        const int q = t & 3;
        const size_t base = ((size_t)(s0 + row) * R_DIM + r) * C_DIM + q * 64;
        const floatx4* gp = reinterpret_cast<const floatx4*>(x + base);
        floatx4 v[16];
        float sum = 0.f, sq = 0.f;
#pragma unroll
        for (int i = 0; i < 16; i++) {
            v[i] = gp[i];
            sum += v[i][0] + v[i][1] + v[i][2] + v[i][3];
            sq  += v[i][0] * v[i][0] + v[i][1] * v[i][1] + v[i][2] * v[i][2] + v[i][3] * v[i][3];
        }
        sum += __shfl_xor(sum, 1); sq += __shfl_xor(sq, 1);
        sum += __shfl_xor(sum, 2); sq += __shfl_xor(sq, 2);
        float mu = sum * (1.f / 256.f);
        float var = sq * (1.f / 256.f) - mu * mu;
        float rs = rsqrtf(var + 1e-5f);
        const floatx4* sp = reinterpret_cast<const floatx4*>(lns + q * 64);
        const floatx4* bp = reinterpret_cast<const floatx4*>(lnb + q * 64);
        unsigned short* wp = xn + row * 264 + q * 64;
#pragma unroll
        for (int i = 0; i < 16; i += 2) {
            floatx4 g0 = sp[i],     b0 = bp[i];
            floatx4 g1 = sp[i + 1], b1 = bp[i + 1];
            ushort8v u;
            u[0] = f2bf((v[i][0]     - mu) * rs * g0[0] + b0[0]);
            u[1] = f2bf((v[i][1]     - mu) * rs * g0[1] + b0[1]);
            u[2] = f2bf((v[i][2]     - mu) * rs * g0[2] + b0[2]);
            u[3] = f2bf((v[i][3]     - mu) * rs * g0[3] + b0[3]);
            u[4] = f2bf((v[i + 1][0] - mu) * rs * g1[0] + b1[0]);
            u[5] = f2bf((v[i + 1][1] - mu) * rs * g1[1] + b1[1]);
            u[6] = f2bf((v[i + 1][2] - mu) * rs * g1[2] + b1[2]);
            u[7] = f2bf((v[i + 1][3] - mu) * rs * g1[3] + b1[3]);
            *reinterpret_cast<ushort8v*>(wp + i * 4) = u;
        }
    }
    if (t < 64) mk[t] = mask[(size_t)(s0 + t) * R_DIM + r];
    __syncthreads();

    const int w = t >> 6, l = t & 63;
    const int lr = l & 15, lk = (l >> 4) * 8;
    floatx4 acc[4] = {};
    const unsigned short* arow = xn + (w * 16 + lr) * 264;
#pragma unroll
    for (int kk = 0; kk < 256; kk += 32) {
        short8 a = *reinterpret_cast<const short8*>(arow + kk + lk);
#pragma unroll
        for (int n = 0; n < 4; n++) {
            short8 b = *reinterpret_cast<const short8*>(wkvT + (n * 16 + lr) * 256 + kk + lk);
            acc[n] = __builtin_amdgcn_mfma_f32_16x16x32_bf16(a, b, acc[n], 0, 0, 0);
        }
    }
    unsigned short* kvp = kv + ((size_t)r * S_DIM + s0) * 64;
#pragma unroll
    for (int n = 0; n < 4; n++) {
        int col = n * 16 + lr;
#pragma unroll
        for (int i = 0; i < 4; i++) {
            int row = w * 16 + (l >> 4) * 4 + i;
            kvp[(size_t)row * 64 + col] = f2bf(acc[n][i]);
        }
    }
    float cs = 0.f;
    const int c = t;
#pragma unroll 8
    for (int row = 0; row < 64; row++) cs += bf2f(xn[row * 264 + c]) * mk[row];
    qsum[((size_t)r * SB + sblk) * 256 + c] = cs;
    if (t < 64) {
        float m = mk[t];
#pragma unroll
        for (int off = 32; off; off >>= 1) m += __shfl_xor(m, off);
        if (t == 0) msum[r * SB + sblk] = m;
    }
}

// ---------------- K2: q_avg, q, softmax (barrier-free), o ------------------
__global__ __launch_bounds__(256) void k2_kernel(
        const float* __restrict__ mask, const float* __restrict__ Wq,
        const float* __restrict__ qsum, const float* __restrict__ msum,
        const unsigned short* __restrict__ kv, float* __restrict__ oout) {
    __shared__ float qavg[256];
    __shared__ float qh[256];
    __shared__ float lg[8][1024];
    __shared__ unsigned short vt[256 * 36];   // v tile, padded rows (72 B)
    const int r = blockIdx.x;
    const int t = threadIdx.x;

    float ms = 0.f;
#pragma unroll
    for (int i = 0; i < SB; i++) ms += msum[r * SB + i];
    float inv = 1.f / (ms + 1e-10f);
    float qs = 0.f;
#pragma unroll
    for (int i = 0; i < SB; i++) qs += qsum[((size_t)r * SB + i) * 256 + t];
    qavg[t] = qs * inv;
    __syncthreads();

    float accq = 0.f;
#pragma unroll 8
    for (int c = 0; c < 256; c++) accq += qavg[c] * Wq[c * 256 + t];
    qh[t] = accq * 0.17677669529663687f;   // CH^-0.5
    __syncthreads();

    const unsigned short* kvr = kv + (size_t)r * S_DIM * 64;
#pragma unroll
    for (int i = 0; i < 4; i++) {
        int s = i * 256 + t;
        float bias = 1e9f * (mask[(size_t)s * R_DIM + r] - 1.f);
        const unsigned int* kp = reinterpret_cast<const unsigned int*>(kvr + (size_t)s * 64);
        float kvals[32];
#pragma unroll
        for (int j = 0; j < 16; j++) {
            unsigned int u = kp[j];
            kvals[2 * j]     = __uint_as_float(u << 16);
            kvals[2 * j + 1] = __uint_as_float(u & 0xffff0000u);
        }
#pragma unroll
        for (int h = 0; h < 8; h++) {
            float d = 0.f;
#pragma unroll
            for (int ch = 0; ch < 32; ch++) d += qh[h * 32 + ch] * kvals[ch];
            lg[h][s] = d + bias;
        }
    }
    __syncthreads();

    // barrier-free softmax: head = t>>5 (half-wave group), rotated bank access
    {
        const int h = t >> 5;
        const int g = t & 31;
        float* lrow = &lg[h][0];
        float mx = -1e30f;
#pragma unroll
        for (int j = 0; j < 32; j++)
            mx = fmaxf(mx, lrow[g * 32 + ((j + g) & 31)]);
#pragma unroll
        for (int off = 16; off; off >>= 1) mx = fmaxf(mx, __shfl_xor(mx, off));
        float vals[32];
        float sm = 0.f;
#pragma unroll
        for (int j = 0; j < 32; j++) {
            float e = __expf(lrow[g * 32 + ((j + g) & 31)] - mx);
            vals[j] = e;
            sm += e;
        }
#pragma unroll
        for (int off = 16; off; off >>= 1) sm += __shfl_xor(sm, off);
        float isv = 1.f / sm;
#pragma unroll
        for (int j = 0; j < 32; j++)
            lrow[g * 32 + ((j + g) & 31)] = vals[j] * isv;
    }
    __syncthreads();

    // o = w @ v via LDS-staged v tiles (broadcast reads)
    const int h = t >> 5, ch = t & 31;
    float o = 0.f;
    for (int st = 0; st < 4; st++) {
        __syncthreads();
        {
            const unsigned short* src = kvr + ((size_t)(st * 256 + t)) * 64 + 32;
            ushort4v* dst = reinterpret_cast<ushort4v*>(vt + t * 36);
#pragma unroll
            for (int j = 0; j < 8; j++)
                dst[j] = *reinterpret_cast<const ushort4v*>(src + 4 * j);
        }
        __syncthreads();
#pragma unroll 8
        for (int sl = 0; sl < 256; sl++)
            o += lg[h][sl + st * 256] * bf2f(vt[sl * 36 + ch]);
    }
    oout[r * 256 + t] = o;
}

// ---------------- K3 (recompute path, fallback) ----------------------------
__global__ __launch_bounds__(256, 4) void k3r_kernel(
        const float* __restrict__ x, const float* __restrict__ lns,
        const float* __restrict__ lnb, const unsigned short* __restrict__ wgT,
        const unsigned short* __restrict__ wfhi, const unsigned short* __restrict__ wflo,
        const float* __restrict__ oin, const float* __restrict__ bg,
        const float* __restrict__ bfv, float* __restrict__ out) {
    __shared__ unsigned short xa[64 * 264];
    const int sblk = blockIdx.x, r = blockIdx.y;
    const int s0 = sblk * BS;
    const int t = threadIdx.x;
    {
        const int row = t >> 2;
        const int q = t & 3;
        const size_t base = ((size_t)(s0 + row) * R_DIM + r) * C_DIM + q * 64;
        const floatx4* gp = reinterpret_cast<const floatx4*>(x + base);
        floatx4 v[16];
        float sum = 0.f, sq = 0.f;
#pragma unroll
        for (int i = 0; i < 16; i++) {
            v[i] = gp[i];
            sum += v[i][0] + v[i][1] + v[i][2] + v[i][3];
            sq  += v[i][0] * v[i][0] + v[i][1] * v[i][1] + v[i][2] * v[i][2] + v[i][3] * v[i][3];
        }
        sum += __shfl_xor(sum, 1); sq += __shfl_xor(sq, 1);
        sum += __shfl_xor(sum, 2); sq += __shfl_xor(sq, 2);
        float mu = sum * (1.f / 256.f);
        float var = sq * (1.f / 256.f) - mu * mu;
        float rs = rsqrtf(var + 1e-5f);
        const floatx4* sp = reinterpret_cast<const floatx4*>(lns + q * 64);
        const floatx4* bp = reinterpret_cast<const floatx4*>(lnb + q * 64);
        unsigned short* wp = xa + row * 264 + q * 64;
#pragma unroll
        for (int i = 0; i < 16; i += 2) {
            floatx4 g0 = sp[i],     b0 = bp[i];
            floatx4 g1 = sp[i + 1], b1 = bp[i + 1];
            ushort8v u;
            u[0] = f2bf((v[i][0]     - mu) * rs * g0[0] + b0[0]);
            u[1] = f2bf((v[i][1]     - mu) * rs * g0[1] + b0[1]);
            u[2] = f2bf((v[i][2]     - mu) * rs * g0[2] + b0[2]);
            u[3] = f2bf((v[i][3]     - mu) * rs * g0[3] + b0[3]);
            u[4] = f2bf((v[i + 1][0] - mu) * rs * g1[0] + b1[0]);
            u[5] = f2bf((v[i + 1][1] - mu) * rs * g1[1] + b1[1]);
            u[6] = f2bf((v[i + 1][2] - mu) * rs * g1[2] + b1[2]);
            u[7] = f2bf((v[i + 1][3] - mu) * rs * g1[3] + b1[3]);
            *reinterpret_cast<ushort8v*>(wp + i * 4) = u;
        }
    }
    __syncthreads();

    const int w = t >> 6, l = t & 63;
    const int lr = l & 15, lk4 = (l >> 4);
    const int colbase = w * 64;

    float bgv[4], ov[4];
#pragma unroll
    for (int n = 0; n < 4; n++) {
        int col = colbase + n * 16 + lr;
        bgv[n] = bg[col];
        ov[n] = oin[r * 256 + col];
    }

    floatx4 acc[4][4] = {};
#pragma unroll
    for (int kk = 0; kk < 256; kk += 32) {
        short8 a[4];
#pragma unroll
        for (int m = 0; m < 4; m++)
            a[m] = *reinterpret_cast<const short8*>(xa + (m * 16 + lr) * 264 + kk + lk4 * 8);
#pragma unroll
        for (int n = 0; n < 4; n++) {
            short8 b = *reinterpret_cast<const short8*>(wgT + (size_t)(colbase + n * 16 + lr) * 256 + kk + lk4 * 8);
#pragma unroll
            for (int m = 0; m < 4; m++)
                acc[m][n] = __builtin_amdgcn_mfma_f32_16x16x32_bf16(a[m], b, acc[m][n], 0, 0, 0);
        }
    }
    __syncthreads();

#pragma unroll
    for (int m = 0; m < 4; m++) {
#pragma unroll
        for (int n = 0; n < 4; n++) {
            int col = colbase + n * 16 + lr;
#pragma unroll
            for (int i = 0; i < 4; i++) {
                int row = m * 16 + lk4 * 4 + i;
                float e = __expf(-(acc[m][n][i] + bgv[n]));
                float g = fast_rcp(1.f + e);
                xa[row * 264 + col] = f2bf(g * ov[n]);
            }
        }
    }
    __syncthreads();

    floatx4 acc2[4][4] = {};
#pragma unroll
    for (int kk = 0; kk < 256; kk += 32) {
        short8 ah[4];
#pragma unroll
        for (int m = 0; m < 4; m++)
            ah[m] = *reinterpret_cast<const short8*>(xa + (m * 16 + lr) * 264 + kk + lk4 * 8);
#pragma unroll
        for (int n = 0; n < 4; n++) {
            const size_t boff = (size_t)(colbase + n * 16 + lr) * 256 + kk + lk4 * 8;
            short8 bh = *reinterpret_cast<const short8*>(wfhi + boff);
            short8 bl = *reinterpret_cast<const short8*>(wflo + boff);
#pragma unroll
            for (int m = 0; m < 4; m++) {
                acc2[m][n] = __builtin_amdgcn_mfma_f32_16x16x32_bf16(ah[m], bh, acc2[m][n], 0, 0, 0);
                acc2[m][n] = __builtin_amdgcn_mfma_f32_16x16x32_bf16(ah[m], bl, acc2[m][n], 0, 0, 0);
            }
        }
    }

#pragma unroll
    for (int n = 0; n < 4; n++) {
        int col = colbase + n * 16 + lr;
        float bfc = bfv[col];
#pragma unroll
        for (int m = 0; m < 4; m++) {
#pragma unroll
            for (int i = 0; i < 4; i++) {
                int row = m * 16 + lk4 * 4 + i;
                out[((size_t)(s0 + row) * R_DIM + r) * C_DIM + col] = acc2[m][n][i] + bfc;
            }
        }
    }
}

// ---------------- K3 (xn-cache path): R12 hybrid (measured best, 333us) ----
// Pass 1 SWAPPED (thread owns 4 contiguous cols -> vectorized gate writes);
// pass 2 + epilogue NON-swapped (full-line stores per 16-lane quarter-wave).
__global__ __launch_bounds__(256, 2) void k3c_kernel(
        const unsigned short* __restrict__ xnws, const unsigned short* __restrict__ wgT,
        const unsigned short* __restrict__ wfhi, const unsigned short* __restrict__ wflo,
        const float* __restrict__ oin, const float* __restrict__ bg,
        const float* __restrict__ bfv, float* __restrict__ out) {
    __shared__ unsigned short xa[2][64 * 256];   // 64 KB, chunk' = chunk ^ (row&7)
    const int sblk = blockIdx.x, r = blockIdx.y;
    const int s0 = sblk * 128;
    const int t = threadIdx.x;
    const int w = t >> 6, l = t & 63;

    // async stage both tiles: LDS linear, source pre-swizzled
    {
        const int c1 = l & 31;
        const int rh = l >> 5;
#pragma unroll
        for (int T = 0; T < 2; T++)
#pragma unroll
            for (int j = 0; j < 8; j++) {
                int row = w * 16 + 2 * j + rh;
                size_t src = ((size_t)(s0 + T * 64 + row) * R_DIM + r) * C_DIM
                             + (size_t)((c1 ^ (row & 7)) * 8);
                async16nt(&xa[T][(w * 16 + 2 * j) * 256], xnws + src);
            }
    }

    const int lr = l & 15, lk4 = (l >> 4);
    const int colbase = w * 64;
    const int sw = lr & 7;            // row&7 for rows m*16+lr
    const int c0 = colbase + lk4 * 4; // 4-contiguous-col base for pass 1 (+n*16)

    floatx4 bg4[4], ov4[4];
    float bfc[4];
#pragma unroll
    for (int n = 0; n < 4; n++) {
        bg4[n] = *reinterpret_cast<const floatx4*>(bg + c0 + n * 16);
        ov4[n] = *reinterpret_cast<const floatx4*>(oin + r * 256 + c0 + n * 16);
        bfc[n] = bfv[colbase + n * 16 + lr];
    }
    __syncthreads();

    // ---- pass 1 (swapped): acc[T][m][n][i] = Z[m*16+lr][c0 + n*16 + i] ----
    floatx4 acc[2][4][4] = {};
    {
        const unsigned short* wgb = wgT + (size_t)(colbase + lr) * 256 + lk4 * 8;
        short8 cw[4], nw[4];
#pragma unroll
        for (int n = 0; n < 4; n++)
            cw[n] = *reinterpret_cast<const short8*>(wgb + n * 4096);
#pragma unroll
        for (int kk = 0; kk < 256; kk += 32) {
            if (kk < 224) {
#pragma unroll
                for (int n = 0; n < 4; n++)
                    nw[n] = *reinterpret_cast<const short8*>(wgb + n * 4096 + kk + 32);
            }
            const int ch = (((kk >> 3) + lk4) ^ sw) * 8;
#pragma unroll
            for (int T = 0; T < 2; T++) {
                short8 a[4];
#pragma unroll
                for (int m = 0; m < 4; m++)
                    a[m] = *reinterpret_cast<const short8*>(&xa[T][(m * 16 + lr) * 256 + ch]);
#pragma unroll
                for (int n = 0; n < 4; n++)
#pragma unroll
                    for (int m = 0; m < 4; m++)
                        acc[T][m][n] = __builtin_amdgcn_mfma_f32_16x16x32_bf16(cw[n], a[m], acc[T][m][n], 0, 0, 0);
            }
            if (kk < 224) {
#pragma unroll
                for (int n = 0; n < 4; n++) cw[n] = nw[n];
            }
        }
    }
    __syncthreads();

    // ---- gate: fast sigmoid -> vectorized ushort4 swizzled LDS writes ----
#pragma unroll
    for (int T = 0; T < 2; T++)
#pragma unroll
    for (int m = 0; m < 4; m++) {
        const int row = m * 16 + lr;
        unsigned short* rowp = &xa[T][row * 256];
#pragma unroll
        for (int n = 0; n < 4; n++) {
            const int cb = c0 + n * 16;
            ushort4v pk;
#pragma unroll
            for (int i = 0; i < 4; i++) {
                float e = __expf(-(acc[T][m][n][i] + ((const float*)&bg4[n])[i]));
                float g = fast_rcp(1.f + e);
                pk[i] = f2bf(g * ((const float*)&ov4[n])[i]);
            }
            const int dst = (((cb >> 3) ^ sw) * 8) + (cb & 7);
            *reinterpret_cast<ushort4v*>(rowp + dst) = pk;
        }
    }
    __syncthreads();

    // ---- pass 2 (non-swapped, R9 form): acc2[T][m][n] row-major stripes ----
    floatx4 acc2[2][4][4] = {};
    {
        const unsigned short* whb = wfhi + (size_t)(colbase + lr) * 256 + lk4 * 8;
        const unsigned short* wlb = wflo + (size_t)(colbase + lr) * 256 + lk4 * 8;
        short8 chw[4], clw[4], nhw[4], nlw[4];
#pragma unroll
        for (int n = 0; n < 4; n++) {
            chw[n] = *reinterpret_cast<const short8*>(whb + n * 4096);
            clw[n] = *reinterpret_cast<const short8*>(wlb + n * 4096);
        }
#pragma unroll
        for (int kk = 0; kk < 256; kk += 32) {
            if (kk < 224) {
#pragma unroll
                for (int n = 0; n < 4; n++) {
                    nhw[n] = *reinterpret_cast<const short8*>(whb + n * 4096 + kk + 32);
                    nlw[n] = *reinterpret_cast<const short8*>(wlb + n * 4096 + kk + 32);
                }
            }
            const int ch = (((kk >> 3) + lk4) ^ sw) * 8;
#pragma unroll
            for (int T = 0; T < 2; T++) {
                short8 ah[4];
#pragma unroll
                for (int m = 0; m < 4; m++)
                    ah[m] = *reinterpret_cast<const short8*>(&xa[T][(m * 16 + lr) * 256 + ch]);
#pragma unroll
                for (int n = 0; n < 4; n++)
#pragma unroll
                    for (int m = 0; m < 4; m++) {
                        acc2[T][m][n] = __builtin_amdgcn_mfma_f32_16x16x32_bf16(ah[m], chw[n], acc2[T][m][n], 0, 0, 0);
                        acc2[T][m][n] = __builtin_amdgcn_mfma_f32_16x16x32_bf16(ah[m], clw[n], acc2[T][m][n], 0, 0, 0);
                    }
            }
            if (kk < 224) {
#pragma unroll
                for (int n = 0; n < 4; n++) { chw[n] = nhw[n]; clw[n] = nlw[n]; }
            }
        }
    }

    // ---- epilogue: CACHED stores (full-line per quarter-wave; L2 merges) ----
#pragma unroll
    for (int T = 0; T < 2; T++)
#pragma unroll
    for (int n = 0; n < 4; n++) {
        int col = colbase + n * 16 + lr;
#pragma unroll
        for (int m = 0; m < 4; m++) {
#pragma unroll
            for (int i = 0; i < 4; i++) {
                int row = T * 64 + m * 16 + lk4 * 4 + i;
                out[((size_t)(s0 + row) * R_DIM + r) * C_DIM + col] = acc2[T][m][n][i] + bfc[n];
            }
        }
    }
}

extern "C" void kernel_launch(void* const* d_in, const int* in_sizes, int n_in,
                              void* d_out, int out_size, void* d_ws, size_t ws_size,
                              hipStream_t stream) {
    const float* x1   = (const float*)d_in[0];
    const float* mask = (const float*)d_in[1];
    const float* lns  = (const float*)d_in[2];
    const float* lnb  = (const float*)d_in[3];
    const float* Wq   = (const float*)d_in[4];
    const float* Wk   = (const float*)d_in[5];
    const float* Wv   = (const float*)d_in[6];
    const float* Wg   = (const float*)d_in[7];
    const float* bg   = (const float*)d_in[8];
    const float* Wf   = (const float*)d_in[9];
    const float* bfv  = (const float*)d_in[10];

    char* ws = (char*)d_ws;
    unsigned short* wgT  = (unsigned short*)(ws);                 // 128 KB
    unsigned short* wfhi = (unsigned short*)(ws + 131072);        // 128 KB
    unsigned short* wflo = (unsigned short*)(ws + 262144);        // 128 KB
    unsigned short* wkvT = (unsigned short*)(ws + 393216);        // 32 KB
    float* qsum = (float*)(ws + 425984);                          // 8 MB
    float* msum = (float*)(ws + 425984 + 8388608);                // 32 KB
    float* oo   = (float*)(ws + 425984 + 8388608 + 32768);        // 512 KB
    unsigned short* xnws = (unsigned short*)(ws + XN_OFF);        // 256 MB (if present)
    // kv scratch lives in d_out; K3 overwrites d_out only after K2 consumed kv
    unsigned short* kv = (unsigned short*)d_out;
    float* out = (float*)d_out;

    const bool big_ws = ws_size >= (size_t)XN_OFF + (size_t)XN_BYTES;

    prep_kernel<<<256, 256, 0, stream>>>(Wk, Wv, Wg, Wf, wgT, wfhi, wflo, wkvT);
    if (big_ws) {
        k1a_kernel<<<(S_DIM * R_DIM) / 32, 256, 0, stream>>>(x1, lns, lnb, xnws);
        k1b_kernel<<<dim3(SB, R_DIM), 256, 0, stream>>>(xnws, mask, wkvT, kv, qsum, msum);
        k2_kernel<<<R_DIM, 256, 0, stream>>>(mask, Wq, qsum, msum, kv, oo);
        k3c_kernel<<<dim3(SB / 2, R_DIM), 256, 0, stream>>>(xnws, wgT, wfhi, wflo, oo, bg, bfv, out);
    } else {
        k1_old_kernel<<<dim3(SB, R_DIM), 256, 0, stream>>>(x1, mask, lns, lnb, wkvT, kv, qsum, msum);
        k2_kernel<<<R_DIM, 256, 0, stream>>>(mask, Wq, qsum, msum, kv, oo);
        k3r_kernel<<<dim3(SB, R_DIM), 256, 0, stream>>>(x1, lns, lnb, wgT, wfhi, wflo, oo, bg, bfv, out);
    }
}

// Round 15
// 694.594 us; speedup vs baseline: 1.1412x; 1.0225x over previous
//
#include <hip/hip_runtime.h>
#include <hip/hip_bf16.h>

#define S_DIM 1024
#define R_DIM 512
#define C_DIM 256
#define BS 64
#define SB (S_DIM / BS)   // 16

#define XN_OFF (16u << 20)                       // xn cache at ws+16MB
#define XN_BYTES (512ull * 1024ull * 256ull * 2ull)  // 268435456

typedef __attribute__((ext_vector_type(8))) short short8;
typedef __attribute__((ext_vector_type(8))) unsigned short ushort8v;
typedef __attribute__((ext_vector_type(4))) unsigned short ushort4v;
typedef __attribute__((ext_vector_type(4))) float floatx4;

__device__ inline float bf2f(unsigned short u) {
    return __uint_as_float(((unsigned int)u) << 16);
}
__device__ inline unsigned short f2bf(float f) {
    unsigned int x = __float_as_uint(f);
    unsigned int r = ((x >> 16) & 1u) + 0x7fffu;
    return (unsigned short)((x + r) >> 16);
}

// v_rcp_f32: ~1ulp approx reciprocal; avoids the IEEE divide sequence.
__device__ inline float fast_rcp(float x) {
    float r;
    asm volatile("v_rcp_f32 %0, %1" : "=v"(r) : "v"(x));
    return r;
}

__device__ inline void async16nt(unsigned short* lds, const unsigned short* g) {
    // aux=2 -> NT cache policy; safe: every 16-lane group covers full lines.
    __builtin_amdgcn_global_load_lds(
        (const __attribute__((address_space(1))) void*)g,
        (__attribute__((address_space(3))) void*)lds, 16, 0, 2);
}
__device__ inline void async16(unsigned short* lds, const unsigned short* g) {
    // cached variant (tile reused within block)
    __builtin_amdgcn_global_load_lds(
        (const __attribute__((address_space(1))) void*)g,
        (__attribute__((address_space(3))) void*)lds, 16, 0, 0);
}

// ---------------- prep: build transposed bf16 weight copies ----------------
__global__ __launch_bounds__(256) void prep_kernel(
        const float* __restrict__ Wk, const float* __restrict__ Wv,
        const float* __restrict__ Wg, const float* __restrict__ Wf,
        unsigned short* __restrict__ wgT, unsigned short* __restrict__ wfhi,
        unsigned short* __restrict__ wflo, unsigned short* __restrict__ wkvT) {
    int b = blockIdx.x;    // output column index (0..255)
    int k = threadIdx.x;   // k index (0..255)
    wgT[b * 256 + k] = f2bf(Wg[k * 256 + b]);
    float w = Wf[k * 256 + b];
    unsigned short hi = f2bf(w);
    wfhi[b * 256 + k] = hi;
    wflo[b * 256 + k] = f2bf(w - bf2f(hi));
    if (b < 64) {
        float t = (b < 32) ? Wk[k * 32 + b] : Wv[k * 32 + (b - 32)];
        wkvT[b * 256 + k] = f2bf(t);
    }
}

// ---------------- K1a: streaming LayerNorm x -> xnws, full-line pattern ----
__global__ __launch_bounds__(256, 4) void k1a_kernel(
        const float* __restrict__ x, const float* __restrict__ lns,
        const float* __restrict__ lnb, unsigned short* __restrict__ xnws) {
    const int t = threadIdx.x;
    const int row = t >> 3;           // 0..31 within block
    const int q = t & 7;
    const size_t rowbase = ((size_t)blockIdx.x * 32 + row) * 256;
    const floatx4* gp = reinterpret_cast<const floatx4*>(x + rowbase);
    const floatx4* sp = reinterpret_cast<const floatx4*>(lns);
    const floatx4* bp = reinterpret_cast<const floatx4*>(lnb);
    floatx4 v[8];
    float sum = 0.f, sq = 0.f;
#pragma unroll
    for (int i = 0; i < 8; i++) {
        v[i] = gp[i * 8 + q];
        sum += v[i][0] + v[i][1] + v[i][2] + v[i][3];
        sq  += v[i][0] * v[i][0] + v[i][1] * v[i][1]
             + v[i][2] * v[i][2] + v[i][3] * v[i][3];
    }
    sum += __shfl_xor(sum, 1); sq += __shfl_xor(sq, 1);
    sum += __shfl_xor(sum, 2); sq += __shfl_xor(sq, 2);
    sum += __shfl_xor(sum, 4); sq += __shfl_xor(sq, 4);
    float mu = sum * (1.f / 256.f);
    float var = sq * (1.f / 256.f) - mu * mu;
    float rs = rsqrtf(var + 1e-5f);
    unsigned short* gw = xnws + rowbase;
#pragma unroll
    for (int i = 0; i < 8; i++) {
        floatx4 g0 = sp[i * 8 + q];
        floatx4 b0 = bp[i * 8 + q];
        ushort4v u;
        u[0] = f2bf((v[i][0] - mu) * rs * g0[0] + b0[0]);
        u[1] = f2bf((v[i][1] - mu) * rs * g0[1] + b0[1]);
        u[2] = f2bf((v[i][2] - mu) * rs * g0[2] + b0[2]);
        u[3] = f2bf((v[i][3] - mu) * rs * g0[3] + b0[3]);
        *reinterpret_cast<ushort4v*>(gw + (i * 8 + q) * 4) = u;
    }
}

// ---------------- K1b: kv + masked column sums from xnws -------------------
__global__ __launch_bounds__(256, 4) void k1b_kernel(
        const unsigned short* __restrict__ xnws, const float* __restrict__ mask,
        const unsigned short* __restrict__ wkvT, unsigned short* __restrict__ kv,
        float* __restrict__ qsum, float* __restrict__ msum) {
    __shared__ unsigned short xn[64 * 256];   // chunk' = chunk ^ (row&7)
    __shared__ float mk[64];
    const int sblk = blockIdx.x, r = blockIdx.y;
    const int s0 = sblk * BS;
    const int t = threadIdx.x;
    const int w = t >> 6, l = t & 63;

    {   // async stage: wave w rows 16w..16w+15; LDS linear, source pre-swizzled
        const int c1 = l & 31;
        const int rh = l >> 5;
#pragma unroll
        for (int j = 0; j < 8; j++) {
            int row = w * 16 + 2 * j + rh;
            size_t src = ((size_t)(s0 + row) * R_DIM + r) * C_DIM
                         + (size_t)((c1 ^ (row & 7)) * 8);
            async16nt(xn + (w * 16 + 2 * j) * 256, xnws + src);
        }
    }
    if (t < 64) mk[t] = mask[(size_t)(s0 + t) * R_DIM + r];
    __syncthreads();

    // MFMA: wave w -> rows 16w..16w+15, cols 0..63 (= [k | v])
    const int lr = l & 15, lk4 = l >> 4;
    const int sw = lr & 7;   // row&7 for row = w*16+lr
    floatx4 acc[4] = {};
#pragma unroll
    for (int kk = 0; kk < 256; kk += 32) {
        const int ch = (((kk >> 3) + lk4) ^ sw) * 8;
        short8 a = *reinterpret_cast<const short8*>(xn + (w * 16 + lr) * 256 + ch);
#pragma unroll
        for (int n = 0; n < 4; n++) {
            short8 b = *reinterpret_cast<const short8*>(wkvT + (n * 16 + lr) * 256 + kk + lk4 * 8);
            acc[n] = __builtin_amdgcn_mfma_f32_16x16x32_bf16(a, b, acc[n], 0, 0, 0);
        }
    }
    unsigned short* kvp = kv + ((size_t)r * S_DIM + s0) * 64;
#pragma unroll
    for (int n = 0; n < 4; n++) {
        int col = n * 16 + lr;
#pragma unroll
        for (int i = 0; i < 4; i++) {
            int row = w * 16 + lk4 * 4 + i;
            kvp[(size_t)row * 64 + col] = f2bf(acc[n][i]);
        }
    }
    // masked column sums over the 64 rows (swizzled column read)
    {
        const int c = t;
        const int chi = c >> 3, clo = c & 7;
        float cs = 0.f;
#pragma unroll 8
        for (int row = 0; row < 64; row++)
            cs += bf2f(xn[row * 256 + ((chi ^ (row & 7)) * 8 + clo)]) * mk[row];
        qsum[((size_t)r * SB + sblk) * 256 + c] = cs;
    }
    if (t < 64) {
        float m = mk[t];
#pragma unroll
        for (int off = 32; off; off >>= 1) m += __shfl_xor(m, off);
        if (t == 0) msum[r * SB + sblk] = m;
    }
}

// ---------------- K1 (fallback, fused, small-ws path) ----------------------
__global__ __launch_bounds__(256, 4) void k1_old_kernel(
        const float* __restrict__ x, const float* __restrict__ mask,
        const float* __restrict__ lns, const float* __restrict__ lnb,
        const unsigned short* __restrict__ wkvT, unsigned short* __restrict__ kv,
        float* __restrict__ qsum, float* __restrict__ msum) {
    __shared__ unsigned short xn[64 * 264];
    __shared__ float mk[64];
    const int sblk = blockIdx.x, r = blockIdx.y;
    const int s0 = sblk * BS;
    const int t = threadIdx.x;
    {
        const int row = t >> 2;
        const int q = t & 3;
        const size_t base = ((size_t)(s0 + row) * R_DIM + r) * C_DIM + q * 64;
        const floatx4* gp = reinterpret_cast<const floatx4*>(x + base);
        floatx4 v[16];
        float sum = 0.f, sq = 0.f;
#pragma unroll
        for (int i = 0; i < 16; i++) {
            v[i] = gp[i];
            sum += v[i][0] + v[i][1] + v[i][2] + v[i][3];
            sq  += v[i][0] * v[i][0] + v[i][1] * v[i][1] + v[i][2] * v[i][2] + v[i][3] * v[i][3];
        }
        sum += __shfl_xor(sum, 1); sq += __shfl_xor(sq, 1);
        sum += __shfl_xor(sum, 2); sq += __shfl_xor(sq, 2);
        float mu = sum * (1.f / 256.f);
        float var = sq * (1.f / 256.f) - mu * mu;
        float rs = rsqrtf(var + 1e-5f);
        const floatx4* sp = reinterpret_cast<const floatx4*>(lns + q * 64);
        const floatx4* bp = reinterpret_cast<const floatx4*>(lnb + q * 64);
        unsigned short* wp = xn + row * 264 + q * 64;
#pragma unroll
        for (int i = 0; i < 16; i += 2) {
            floatx4 g0 = sp[i],     b0 = bp[i];
            floatx4 g1 = sp[i + 1], b1 = bp[i + 1];
            ushort8v u;
            u[0] = f2bf((v[i][0]     - mu) * rs * g0[0] + b0[0]);
            u[1] = f2bf((v[i][1]     - mu) * rs * g0[1] + b0[1]);
            u[2] = f2bf((v[i][2]     - mu) * rs * g0[2] + b0[2]);
            u[3] = f2bf((v[i][3]     - mu) * rs * g0[3] + b0[3]);
            u[4] = f2bf((v[i + 1][0] - mu) * rs * g1[0] + b1[0]);
            u[5] = f2bf((v[i + 1][1] - mu) * rs * g1[1] + b1[1]);
            u[6] = f2bf((v[i + 1][2] - mu) * rs * g1[2] + b1[2]);
            u[7] = f2bf((v[i + 1][3] - mu) * rs * g1[3] + b1[3]);
            *reinterpret_cast<ushort8v*>(wp + i * 4) = u;
        }
    }
    if (t < 64) mk[t] = mask[(size_t)(s0 + t) * R_DIM + r];
    __syncthreads();

    const int w = t >> 6, l = t & 63;
    const int lr = l & 15, lk = (l >> 4) * 8;
    floatx4 acc[4] = {};
    const unsigned short* arow = xn + (w * 16 + lr) * 264;
#pragma unroll
    for (int kk = 0; kk < 256; kk += 32) {
        short8 a = *reinterpret_cast<const short8*>(arow + kk + lk);
#pragma unroll
        for (int n = 0; n < 4; n++) {
            short8 b = *reinterpret_cast<const short8*>(wkvT + (n * 16 + lr) * 256 + kk + lk);
            acc[n] = __builtin_amdgcn_mfma_f32_16x16x32_bf16(a, b, acc[n], 0, 0, 0);
        }
    }
    unsigned short* kvp = kv + ((size_t)r * S_DIM + s0) * 64;
#pragma unroll
    for (int n = 0; n < 4; n++) {
        int col = n * 16 + lr;
#pragma unroll
        for (int i = 0; i < 4; i++) {
            int row = w * 16 + (l >> 4) * 4 + i;
            kvp[(size_t)row * 64 + col] = f2bf(acc[n][i]);
        }
    }
    float cs = 0.f;
    const int c = t;
#pragma unroll 8
    for (int row = 0; row < 64; row++) cs += bf2f(xn[row * 264 + c]) * mk[row];
    qsum[((size_t)r * SB + sblk) * 256 + c] = cs;
    if (t < 64) {
        float m = mk[t];
#pragma unroll
        for (int off = 32; off; off >>= 1) m += __shfl_xor(m, off);
        if (t == 0) msum[r * SB + sblk] = m;
    }
}

// ---------------- K2: q_avg, q, softmax, o — LDS-staged kv tiles -----------
// Logits: stage full 128B kv rows per 256-s tile (full-line async, swizzled
// chunks ^(row&7)); k read from LDS. o-pass: re-stage v-halves (64B lines,
// swizzle ^(row&3)) into the same buffer. No uncoalesced global reads left.
__global__ __launch_bounds__(256) void k2_kernel(
        const float* __restrict__ mask, const float* __restrict__ Wq,
        const float* __restrict__ qsum, const float* __restrict__ msum,
        const unsigned short* __restrict__ kv, float* __restrict__ oout) {
    __shared__ float qavg[256];
    __shared__ float qh[256];
    __shared__ float lg[8][1024];
    __shared__ unsigned short kt[256 * 64];   // 32KB staged tile (reused as 16KB v-tile)
    const int r = blockIdx.x;
    const int t = threadIdx.x;
    const int w = t >> 6, l = t & 63;

    float ms = 0.f;
#pragma unroll
    for (int i = 0; i < SB; i++) ms += msum[r * SB + i];
    float inv = 1.f / (ms + 1e-10f);
    float qs = 0.f;
#pragma unroll
    for (int i = 0; i < SB; i++) qs += qsum[((size_t)r * SB + i) * 256 + t];
    qavg[t] = qs * inv;
    __syncthreads();

    float accq = 0.f;
#pragma unroll 8
    for (int c = 0; c < 256; c++) accq += qavg[c] * Wq[c * 256 + t];
    qh[t] = accq * 0.17677669529663687f;   // CH^-0.5
    __syncthreads();

    const unsigned short* kvr = kv + (size_t)r * S_DIM * 64;

    // ---- logits: 4 tiles of 256 s, k from staged LDS ----
    for (int st = 0; st < 4; st++) {
        {   // stage full rows: instr j covers rows w*64+j*8..+7, 8 chunks each
#pragma unroll
            for (int j = 0; j < 8; j++) {
                int row = w * 64 + j * 8 + (l >> 3);
                int c = l & 7;
                const unsigned short* src = kvr + (size_t)(st * 256 + row) * 64
                                            + ((c ^ (row & 7)) * 8);
                async16(kt + (w * 64 + j * 8) * 64, src);
            }
        }
        __syncthreads();
        {
            int s = st * 256 + t;
            float bias = 1e9f * (mask[(size_t)s * R_DIM + r] - 1.f);
            float kvals[32];
#pragma unroll
            for (int j = 0; j < 4; j++) {
                ushort8v u8 = *reinterpret_cast<const ushort8v*>(
                    kt + t * 64 + ((j ^ (t & 7)) * 8));
#pragma unroll
                for (int e = 0; e < 8; e++) kvals[j * 8 + e] = bf2f(u8[e]);
            }
#pragma unroll
            for (int h = 0; h < 8; h++) {
                float d = 0.f;
#pragma unroll
                for (int ch = 0; ch < 32; ch++) d += qh[h * 32 + ch] * kvals[ch];
                lg[h][s] = d + bias;
            }
        }
        __syncthreads();   // lg tile written; kt free for next stage
    }

    // ---- barrier-free softmax: head = t>>5, rotated bank access ----
    {
        const int h = t >> 5;
        const int g = t & 31;
        float* lrow = &lg[h][0];
        float mx = -1e30f;
#pragma unroll
        for (int j = 0; j < 32; j++)
            mx = fmaxf(mx, lrow[g * 32 + ((j + g) & 31)]);
#pragma unroll
        for (int off = 16; off; off >>= 1) mx = fmaxf(mx, __shfl_xor(mx, off));
        float vals[32];
        float sm = 0.f;
#pragma unroll
        for (int j = 0; j < 32; j++) {
            float e = __expf(lrow[g * 32 + ((j + g) & 31)] - mx);
            vals[j] = e;
            sm += e;
        }
#pragma unroll
        for (int off = 16; off; off >>= 1) sm += __shfl_xor(sm, off);
        float isv = 1.f / sm;
#pragma unroll
        for (int j = 0; j < 32; j++)
            lrow[g * 32 + ((j + g) & 31)] = vals[j] * isv;
    }

    // ---- o = w @ v: re-stage v-halves per tile (64B lines) ----
    const int h = t >> 5, ch = t & 31;
    const int c3 = ch >> 3, ce = ch & 7;
    float o = 0.f;
    for (int st = 0; st < 4; st++) {
        __syncthreads();   // softmax/lg visible; prior tile reads done
        {   // stage v: instr j covers rows w*64+j*16..+15, 4 chunks each
#pragma unroll
            for (int j = 0; j < 4; j++) {
                int row = w * 64 + j * 16 + (l >> 2);
                int c = l & 3;
                const unsigned short* src = kvr + (size_t)(st * 256 + row) * 64 + 32
                                            + ((c ^ (row & 3)) * 8);
                async16(kt + (w * 64 + j * 16) * 32, src);
            }
        }
        __syncthreads();
        const float* lrow = &lg[h][st * 256];
#pragma unroll 8
        for (int sl = 0; sl < 256; sl++)
            o += lrow[sl] * bf2f(kt[sl * 32 + ((c3 ^ (sl & 3)) * 8 + ce)]);
    }
    oout[r * 256 + t] = o;
}

// ---------------- K3 (recompute path, fallback) ----------------------------
__global__ __launch_bounds__(256, 4) void k3r_kernel(
        const float* __restrict__ x, const float* __restrict__ lns,
        const float* __restrict__ lnb, const unsigned short* __restrict__ wgT,
        const unsigned short* __restrict__ wfhi, const unsigned short* __restrict__ wflo,
        const float* __restrict__ oin, const float* __restrict__ bg,
        const float* __restrict__ bfv, float* __restrict__ out) {
    __shared__ unsigned short xa[64 * 264];
    const int sblk = blockIdx.x, r = blockIdx.y;
    const int s0 = sblk * BS;
    const int t = threadIdx.x;
    {
        const int row = t >> 2;
        const int q = t & 3;
        const size_t base = ((size_t)(s0 + row) * R_DIM + r) * C_DIM + q * 64;
        const floatx4* gp = reinterpret_cast<const floatx4*>(x + base);
        floatx4 v[16];
        float sum = 0.f, sq = 0.f;
#pragma unroll
        for (int i = 0; i < 16; i++) {
            v[i] = gp[i];
            sum += v[i][0] + v[i][1] + v[i][2] + v[i][3];
            sq  += v[i][0] * v[i][0] + v[i][1] * v[i][1] + v[i][2] * v[i][2] + v[i][3] * v[i][3];
        }
        sum += __shfl_xor(sum, 1); sq += __shfl_xor(sq, 1);
        sum += __shfl_xor(sum, 2); sq += __shfl_xor(sq, 2);
        float mu = sum * (1.f / 256.f);
        float var = sq * (1.f / 256.f) - mu * mu;
        float rs = rsqrtf(var + 1e-5f);
        const floatx4* sp = reinterpret_cast<const floatx4*>(lns + q * 64);
        const floatx4* bp = reinterpret_cast<const floatx4*>(lnb + q * 64);
        unsigned short* wp = xa + row * 264 + q * 64;
#pragma unroll
        for (int i = 0; i < 16; i += 2) {
            floatx4 g0 = sp[i],     b0 = bp[i];
            floatx4 g1 = sp[i + 1], b1 = bp[i + 1];
            ushort8v u;
            u[0] = f2bf((v[i][0]     - mu) * rs * g0[0] + b0[0]);
            u[1] = f2bf((v[i][1]     - mu) * rs * g0[1] + b0[1]);
            u[2] = f2bf((v[i][2]     - mu) * rs * g0[2] + b0[2]);
            u[3] = f2bf((v[i][3]     - mu) * rs * g0[3] + b0[3]);
            u[4] = f2bf((v[i + 1][0] - mu) * rs * g1[0] + b1[0]);
            u[5] = f2bf((v[i + 1][1] - mu) * rs * g1[1] + b1[1]);
            u[6] = f2bf((v[i + 1][2] - mu) * rs * g1[2] + b1[2]);
            u[7] = f2bf((v[i + 1][3] - mu) * rs * g1[3] + b1[3]);
            *reinterpret_cast<ushort8v*>(wp + i * 4) = u;
        }
    }
    __syncthreads();

    const int w = t >> 6, l = t & 63;
    const int lr = l & 15, lk4 = (l >> 4);
    const int colbase = w * 64;

    float bgv[4], ov[4];
#pragma unroll
    for (int n = 0; n < 4; n++) {
        int col = colbase + n * 16 + lr;
        bgv[n] = bg[col];
        ov[n] = oin[r * 256 + col];
    }

    floatx4 acc[4][4] = {};
#pragma unroll
    for (int kk = 0; kk < 256; kk += 32) {
        short8 a[4];
#pragma unroll
        for (int m = 0; m < 4; m++)
            a[m] = *reinterpret_cast<const short8*>(xa + (m * 16 + lr) * 264 + kk + lk4 * 8);
#pragma unroll
        for (int n = 0; n < 4; n++) {
            short8 b = *reinterpret_cast<const short8*>(wgT + (size_t)(colbase + n * 16 + lr) * 256 + kk + lk4 * 8);
#pragma unroll
            for (int m = 0; m < 4; m++)
                acc[m][n] = __builtin_amdgcn_mfma_f32_16x16x32_bf16(a[m], b, acc[m][n], 0, 0, 0);
        }
    }
    __syncthreads();

#pragma unroll
    for (int m = 0; m < 4; m++) {
#pragma unroll
        for (int n = 0; n < 4; n++) {
            int col = colbase + n * 16 + lr;
#pragma unroll
            for (int i = 0; i < 4; i++) {
                int row = m * 16 + lk4 * 4 + i;
                float e = __expf(-(acc[m][n][i] + bgv[n]));
                float g = fast_rcp(1.f + e);
                xa[row * 264 + col] = f2bf(g * ov[n]);
            }
        }
    }
    __syncthreads();

    floatx4 acc2[4][4] = {};
#pragma unroll
    for (int kk = 0; kk < 256; kk += 32) {
        short8 ah[4];
#pragma unroll
        for (int m = 0; m < 4; m++)
            ah[m] = *reinterpret_cast<const short8*>(xa + (m * 16 + lr) * 264 + kk + lk4 * 8);
#pragma unroll
        for (int n = 0; n < 4; n++) {
            const size_t boff = (size_t)(colbase + n * 16 + lr) * 256 + kk + lk4 * 8;
            short8 bh = *reinterpret_cast<const short8*>(wfhi + boff);
            short8 bl = *reinterpret_cast<const short8*>(wflo + boff);
#pragma unroll
            for (int m = 0; m < 4; m++) {
                acc2[m][n] = __builtin_amdgcn_mfma_f32_16x16x32_bf16(ah[m], bh, acc2[m][n], 0, 0, 0);
                acc2[m][n] = __builtin_amdgcn_mfma_f32_16x16x32_bf16(ah[m], bl, acc2[m][n], 0, 0, 0);
            }
        }
    }

#pragma unroll
    for (int n = 0; n < 4; n++) {
        int col = colbase + n * 16 + lr;
        float bfc = bfv[col];
#pragma unroll
        for (int m = 0; m < 4; m++) {
#pragma unroll
            for (int i = 0; i < 4; i++) {
                int row = m * 16 + lk4 * 4 + i;
                out[((size_t)(s0 + row) * R_DIM + r) * C_DIM + col] = acc2[m][n][i] + bfc;
            }
        }
    }
}

// ---------------- K3 (xn-cache path): R12 hybrid (measured best) -----------
__global__ __launch_bounds__(256, 2) void k3c_kernel(
        const unsigned short* __restrict__ xnws, const unsigned short* __restrict__ wgT,
        const unsigned short* __restrict__ wfhi, const unsigned short* __restrict__ wflo,
        const float* __restrict__ oin, const float* __restrict__ bg,
        const float* __restrict__ bfv, float* __restrict__ out) {
    __shared__ unsigned short xa[2][64 * 256];   // 64 KB, chunk' = chunk ^ (row&7)
    const int sblk = blockIdx.x, r = blockIdx.y;
    const int s0 = sblk * 128;
    const int t = threadIdx.x;
    const int w = t >> 6, l = t & 63;

    // async stage both tiles: LDS linear, source pre-swizzled
    {
        const int c1 = l & 31;
        const int rh = l >> 5;
#pragma unroll
        for (int T = 0; T < 2; T++)
#pragma unroll
            for (int j = 0; j < 8; j++) {
                int row = w * 16 + 2 * j + rh;
                size_t src = ((size_t)(s0 + T * 64 + row) * R_DIM + r) * C_DIM
                             + (size_t)((c1 ^ (row & 7)) * 8);
                async16nt(&xa[T][(w * 16 + 2 * j) * 256], xnws + src);
            }
    }

    const int lr = l & 15, lk4 = (l >> 4);
    const int colbase = w * 64;
    const int sw = lr & 7;            // row&7 for rows m*16+lr
    const int c0 = colbase + lk4 * 4; // 4-contiguous-col base for pass 1 (+n*16)

    floatx4 bg4[4], ov4[4];
    float bfc[4];
#pragma unroll
    for (int n = 0; n < 4; n++) {
        bg4[n] = *reinterpret_cast<const floatx4*>(bg + c0 + n * 16);
        ov4[n] = *reinterpret_cast<const floatx4*>(oin + r * 256 + c0 + n * 16);
        bfc[n] = bfv[colbase + n * 16 + lr];
    }
    __syncthreads();

    // ---- pass 1 (swapped): acc[T][m][n][i] = Z[m*16+lr][c0 + n*16 + i] ----
    floatx4 acc[2][4][4] = {};
    {
        const unsigned short* wgb = wgT + (size_t)(colbase + lr) * 256 + lk4 * 8;
        short8 cw[4], nw[4];
#pragma unroll
        for (int n = 0; n < 4; n++)
            cw[n] = *reinterpret_cast<const short8*>(wgb + n * 4096);
#pragma unroll
        for (int kk = 0; kk < 256; kk += 32) {
            if (kk < 224) {
#pragma unroll
                for (int n = 0; n < 4; n++)
                    nw[n] = *reinterpret_cast<const short8*>(wgb + n * 4096 + kk + 32);
            }
            const int ch = (((kk >> 3) + lk4) ^ sw) * 8;
#pragma unroll
            for (int T = 0; T < 2; T++) {
                short8 a[4];
#pragma unroll
                for (int m = 0; m < 4; m++)
                    a[m] = *reinterpret_cast<const short8*>(&xa[T][(m * 16 + lr) * 256 + ch]);
#pragma unroll
                for (int n = 0; n < 4; n++)
#pragma unroll
                    for (int m = 0; m < 4; m++)
                        acc[T][m][n] = __builtin_amdgcn_mfma_f32_16x16x32_bf16(cw[n], a[m], acc[T][m][n], 0, 0, 0);
            }
            if (kk < 224) {
#pragma unroll
                for (int n = 0; n < 4; n++) cw[n] = nw[n];
            }
        }
    }
    __syncthreads();

    // ---- gate: fast sigmoid -> vectorized ushort4 swizzled LDS writes ----
#pragma unroll
    for (int T = 0; T < 2; T++)
#pragma unroll
    for (int m = 0; m < 4; m++) {
        const int row = m * 16 + lr;
        unsigned short* rowp = &xa[T][row * 256];
#pragma unroll
        for (int n = 0; n < 4; n++) {
            const int cb = c0 + n * 16;
            ushort4v pk;
#pragma unroll
            for (int i = 0; i < 4; i++) {
                float e = __expf(-(acc[T][m][n][i] + ((const float*)&bg4[n])[i]));
                float g = fast_rcp(1.f + e);
                pk[i] = f2bf(g * ((const float*)&ov4[n])[i]);
            }
            const int dst = (((cb >> 3) ^ sw) * 8) + (cb & 7);
            *reinterpret_cast<ushort4v*>(rowp + dst) = pk;
        }
    }
    __syncthreads();

    // ---- pass 2 (non-swapped): acc2[T][m][n] row-major stripes ----
    floatx4 acc2[2][4][4] = {};
    {
        const unsigned short* whb = wfhi + (size_t)(colbase + lr) * 256 + lk4 * 8;
        const unsigned short* wlb = wflo + (size_t)(colbase + lr) * 256 + lk4 * 8;
        short8 chw[4], clw[4], nhw[4], nlw[4];
#pragma unroll
        for (int n = 0; n < 4; n++) {
            chw[n] = *reinterpret_cast<const short8*>(whb + n * 4096);
            clw[n] = *reinterpret_cast<const short8*>(wlb + n * 4096);
        }
#pragma unroll
        for (int kk = 0; kk < 256; kk += 32) {
            if (kk < 224) {
#pragma unroll
                for (int n = 0; n < 4; n++) {
                    nhw[n] = *reinterpret_cast<const short8*>(whb + n * 4096 + kk + 32);
                    nlw[n] = *reinterpret_cast<const short8*>(wlb + n * 4096 + kk + 32);
                }
            }
            const int ch = (((kk >> 3) + lk4) ^ sw) * 8;
#pragma unroll
            for (int T = 0; T < 2; T++) {
                short8 ah[4];
#pragma unroll
                for (int m = 0; m < 4; m++)
                    ah[m] = *reinterpret_cast<const short8*>(&xa[T][(m * 16 + lr) * 256 + ch]);
#pragma unroll
                for (int n = 0; n < 4; n++)
#pragma unroll
                    for (int m = 0; m < 4; m++) {
                        acc2[T][m][n] = __builtin_amdgcn_mfma_f32_16x16x32_bf16(ah[m], chw[n], acc2[T][m][n], 0, 0, 0);
                        acc2[T][m][n] = __builtin_amdgcn_mfma_f32_16x16x32_bf16(ah[m], clw[n], acc2[T][m][n], 0, 0, 0);
                    }
            }
            if (kk < 224) {
#pragma unroll
                for (int n = 0; n < 4; n++) { chw[n] = nhw[n]; clw[n] = nlw[n]; }
            }
        }
    }

    // ---- epilogue: CACHED stores (full-line per quarter-wave; L2 merges) ----
#pragma unroll
    for (int T = 0; T < 2; T++)
#pragma unroll
    for (int n = 0; n < 4; n++) {
        int col = colbase + n * 16 + lr;
#pragma unroll
        for (int m = 0; m < 4; m++) {
#pragma unroll
            for (int i = 0; i < 4; i++) {
                int row = T * 64 + m * 16 + lk4 * 4 + i;
                out[((size_t)(s0 + row) * R_DIM + r) * C_DIM + col] = acc2[T][m][n][i] + bfc[n];
            }
        }
    }
}

extern "C" void kernel_launch(void* const* d_in, const int* in_sizes, int n_in,
                              void* d_out, int out_size, void* d_ws, size_t ws_size,
                              hipStream_t stream) {
    const float* x1   = (const float*)d_in[0];
    const float* mask = (const float*)d_in[1];
    const float* lns  = (const float*)d_in[2];
    const float* lnb  = (const float*)d_in[3];
    const float* Wq   = (const float*)d_in[4];
    const float* Wk   = (const float*)d_in[5];
    const float* Wv   = (const float*)d_in[6];
    const float* Wg   = (const float*)d_in[7];
    const float* bg   = (const float*)d_in[8];
    const float* Wf   = (const float*)d_in[9];
    const float* bfv  = (const float*)d_in[10];

    char* ws = (char*)d_ws;
    unsigned short* wgT  = (unsigned short*)(ws);                 // 128 KB
    unsigned short* wfhi = (unsigned short*)(ws + 131072);        // 128 KB
    unsigned short* wflo = (unsigned short*)(ws + 262144);        // 128 KB
    unsigned short* wkvT = (unsigned short*)(ws + 393216);        // 32 KB
    float* qsum = (float*)(ws + 425984);                          // 8 MB
    float* msum = (float*)(ws + 425984 + 8388608);                // 32 KB
    float* oo   = (float*)(ws + 425984 + 8388608 + 32768);        // 512 KB
    unsigned short* xnws = (unsigned short*)(ws + XN_OFF);        // 256 MB (if present)
    // kv scratch lives in d_out; K3 overwrites d_out only after K2 consumed kv
    unsigned short* kv = (unsigned short*)d_out;
    float* out = (float*)d_out;

    const bool big_ws = ws_size >= (size_t)XN_OFF + (size_t)XN_BYTES;

    prep_kernel<<<256, 256, 0, stream>>>(Wk, Wv, Wg, Wf, wgT, wfhi, wflo, wkvT);
    if (big_ws) {
        k1a_kernel<<<(S_DIM * R_DIM) / 32, 256, 0, stream>>>(x1, lns, lnb, xnws);
        k1b_kernel<<<dim3(SB, R_DIM), 256, 0, stream>>>(xnws, mask, wkvT, kv, qsum, msum);
        k2_kernel<<<R_DIM, 256, 0, stream>>>(mask, Wq, qsum, msum, kv, oo);
        k3c_kernel<<<dim3(SB / 2, R_DIM), 256, 0, stream>>>(xnws, wgT, wfhi, wflo, oo, bg, bfv, out);
    } else {
        k1_old_kernel<<<dim3(SB, R_DIM), 256, 0, stream>>>(x1, mask, lns, lnb, wkvT, kv, qsum, msum);
        k2_kernel<<<R_DIM, 256, 0, stream>>>(mask, Wq, qsum, msum, kv, oo);
        k3r_kernel<<<dim3(SB, R_DIM), 256, 0, stream>>>(x1, lns, lnb, wgT, wfhi, wflo, oo, bg, bfv, out);
    }
}